// Round 5
// baseline (38.857 us; speedup 1.0000x reference)
//
#include <hip/hip_runtime.h>
#include <math.h>

#define NPT 320
#define DDIM 256
#define NN2 (NPT*NPT)          // 102400
#define MINN 1e-15f

#define CHUNKS 5
#define PLANE4 (NN2/4)         // 25600 int4 per plane
#define CHUNK4 (PLANE4/CHUNKS) // 5120 int4 per chunk
#define ITERS  (CHUNK4/256)    // 20 int4 per thread
#define NBLK   (NPT*CHUNKS)    // 1600 blocks

// ---------------- fused: row stats + dm tile ----------------
__global__ __launch_bounds__(256) void k_pre(const float* __restrict__ off,
                                             const float* __restrict__ nrm,
                                             const float* __restrict__ curv,
                                             float* __restrict__ dm) {
    __shared__ float sOI[16][260];
    __shared__ float sOJ[16][260];
    __shared__ float sNJ[16][260];
    __shared__ float sx2i[16], sx2j[16], snnj[16], spaj[16];
    const float c = curv[0];
    const float sqrtc = sqrtf(c);
    const int I0 = blockIdx.y * 16, J0 = blockIdx.x * 16;
    const int t = threadIdx.x;
    const int r = t >> 4;
    const int cc = t & 15;
    const int cb = cc << 4;     // 16 floats per thread

    const float4* pOI = (const float4*)&off[(I0 + r) * DDIM + cb];
    const float4* pOJ = (const float4*)&off[(J0 + r) * DDIM + cb];
    const float4* pNJ = (const float4*)&nrm[(J0 + r) * DDIM + cb];
#pragma unroll
    for (int q = 0; q < 4; ++q) {
        *(float4*)&sOI[r][cb + 4 * q] = pOI[q];
        *(float4*)&sOJ[r][cb + 4 * q] = pOJ[q];
        *(float4*)&sNJ[r][cb + 4 * q] = pNJ[q];
    }
    __syncthreads();

    // per-row stats computed in-tile: x2_i, x2_j, nn_j, pa_j
    float a0 = 0.f, a1 = 0.f, a2 = 0.f, a3 = 0.f;
#pragma unroll
    for (int q = 0; q < 16; ++q) {
        const float oi = sOI[r][cb + q];
        const float oj = sOJ[r][cb + q];
        const float nj = sNJ[r][cb + q];
        a0 = fmaf(oi, oi, a0);
        a1 = fmaf(oj, oj, a1);
        a2 = fmaf(nj, nj, a2);
        a3 = fmaf(oj, nj, a3);
    }
    for (int o = 1; o < 16; o <<= 1) {
        a0 += __shfl_xor(a0, o);
        a1 += __shfl_xor(a1, o);
        a2 += __shfl_xor(a2, o);
        a3 += __shfl_xor(a3, o);
    }
    if (cc == 0) { sx2i[r] = a0; sx2j[r] = a1; snnj[r] = a2; spaj[r] = a3; }
    __syncthreads();

    const int ti = t >> 4, tj = t & 15;
    // float4 LDS reads: ds_read_b128, 3 per 4 dims (rows are 1040B = 16B-aligned)
    const float4* rI = (const float4*)&sOI[ti][0];
    const float4* rJ = (const float4*)&sOJ[tj][0];
    const float4* rN = (const float4*)&sNJ[tj][0];
    float g = 0.f, h = 0.f;
#pragma unroll 4
    for (int d4 = 0; d4 < DDIM / 4; ++d4) {
        const float4 ai = rI[d4];
        const float4 bj = rJ[d4];
        const float4 nj = rN[d4];
        g = fmaf(ai.x, bj.x, g); g = fmaf(ai.y, bj.y, g);
        g = fmaf(ai.z, bj.z, g); g = fmaf(ai.w, bj.w, g);
        h = fmaf(ai.x, nj.x, h); h = fmaf(ai.y, nj.y, h);
        h = fmaf(ai.z, nj.z, h); h = fmaf(ai.w, nj.w, h);
    }

    const float x2i = sx2i[ti], x2j = sx2j[tj], nnj = snnj[tj], paj = spaj[tj];
    const float cu = 1.f - 2.f * c * g + c * x2i;
    const float cv = 1.f - c * x2j;
    float den0 = 1.f - 2.f * c * g + c * c * x2i * x2j;
    den0 = fmaxf(den0, MINN);
    float dn2 = (cu * cu * x2j - 2.f * cu * cv * g + cv * cv * x2i) / (den0 * den0);
    dn2 = fmaxf(dn2, MINN);
    const float sc = cv * (cv * h - cu * paj) / den0;
    const float an = fmaxf(fabsf(cv) * sqrtf(nnj), MINN);
    const float numv = 2.f * sqrtc * sc;
    const float denv = fmaxf((1.f - c * dn2) * an, MINN);
    const float z = numv / denv;
    const float dist = asinhf(z) / sqrtc;
    dm[(I0 + ti) * NPT + (J0 + tj)] = expf(dist);
}

// ---------------- triplet scan: partials, NO atomics, depth-8 pipeline ----------------
__global__ __launch_bounds__(256) void k_trip(const int* __restrict__ mask,
                                              const float* __restrict__ dm,
                                              double* __restrict__ psum,
                                              unsigned* __restrict__ pcnt) {
    __shared__ __align__(16) float dmrow[NPT];
    const int bx = blockIdx.x;
    const int i = bx / CHUNKS;
    const int chunk = bx - i * CHUNKS;
    const int t = threadIdx.x;

    for (int v = t; v < NPT; v += 256) dmrow[v] = dm[i * NPT + v];
    __syncthreads();

    const int4* m4 = (const int4*)mask + (size_t)i * PLANE4 + (size_t)chunk * CHUNK4;
    const float4* dm4 = (const float4*)dmrow;

    float s = 0.f;
    unsigned cnt = 0;

#define PROC(B, U) { \
        const unsigned lin = (unsigned)(chunk * CHUNK4 + t + 256 * (U)); \
        const unsigned jj = lin / 80u; \
        const unsigned k4 = lin - jj * 80u; \
        const float dij = dmrow[jj]; \
        const float4 dk = dm4[k4]; \
        const float t0 = dk.x - dij, t1 = dk.y - dij, t2 = dk.z - dij, t3 = dk.w - dij; \
        const bool p0 = (B).x && (t0 > 1e-16f); \
        const bool p1 = (B).y && (t1 > 1e-16f); \
        const bool p2 = (B).z && (t2 > 1e-16f); \
        const bool p3 = (B).w && (t3 > 1e-16f); \
        s += p0 ? t0 : 0.f; cnt += p0; \
        s += p1 ? t1 : 0.f; cnt += p1; \
        s += p2 ? t2 : 0.f; cnt += p2; \
        s += p3 ? t3 : 0.f; cnt += p3; }

    // depth-8 two-bank pipeline: 8 int4 in flight, consume 4 / issue 4
    int4 a0 = m4[t],        a1 = m4[t + 256],  a2 = m4[t + 512],  a3 = m4[t + 768];
    int4 c0 = m4[t + 1024], c1 = m4[t + 1280], c2 = m4[t + 1536], c3 = m4[t + 1792];
#pragma unroll 1
    for (int g = 0; g < 3; ++g) {
        const int nb = (g + 2) * 1024 + t;
        const int4 n0 = m4[nb];
        const int4 n1 = m4[nb + 256];
        const int4 n2 = m4[nb + 512];
        const int4 n3 = m4[nb + 768];
        PROC(a0, 4 * g + 0)
        PROC(a1, 4 * g + 1)
        PROC(a2, 4 * g + 2)
        PROC(a3, 4 * g + 3)
        a0 = c0; a1 = c1; a2 = c2; a3 = c3;
        c0 = n0; c1 = n1; c2 = n2; c3 = n3;
    }
    PROC(a0, 12)
    PROC(a1, 13)
    PROC(a2, 14)
    PROC(a3, 15)
    PROC(c0, 16)
    PROC(c1, 17)
    PROC(c2, 18)
    PROC(c3, 19)
#undef PROC

    // wave reduce (64 lanes), f64 from here on
    double sd = (double)s;
    for (int o = 32; o; o >>= 1) {
        sd += __shfl_down(sd, o);
        cnt += __shfl_down(cnt, o);
    }
    __shared__ double ss[4];
    __shared__ unsigned scn[4];
    const int w = t >> 6;
    if ((t & 63) == 0) { ss[w] = sd; scn[w] = cnt; }
    __syncthreads();
    if (t == 0) {
        psum[bx] = ss[0] + ss[1] + ss[2] + ss[3];
        pcnt[bx] = scn[0] + scn[1] + scn[2] + scn[3];
    }
}

// ---------------- final reduce of 1600 partials ----------------
__global__ __launch_bounds__(256) void k_fin(const double* __restrict__ psum,
                                             const unsigned* __restrict__ pcnt,
                                             float* __restrict__ out) {
    const int t = threadIdx.x;
    double s = 0.0;
    unsigned long long c = 0ULL;
    for (int v = t; v < NBLK; v += 256) {
        s += psum[v];
        c += (unsigned long long)pcnt[v];
    }
    for (int o = 32; o; o >>= 1) {
        s += __shfl_down(s, o);
        c += __shfl_down(c, o);
    }
    __shared__ double ss[4];
    __shared__ unsigned long long sc[4];
    const int w = t >> 6;
    if ((t & 63) == 0) { ss[w] = s; sc[w] = c; }
    __syncthreads();
    if (t == 0) {
        const double S = ss[0] + ss[1] + ss[2] + ss[3];
        unsigned long long C = sc[0] + sc[1] + sc[2] + sc[3];
        if (C == 0ULL) C = 1ULL;
        out[0] = (float)(S / (double)C);
    }
}

extern "C" void kernel_launch(void* const* d_in, const int* in_sizes, int n_in,
                              void* d_out, int out_size, void* d_ws, size_t ws_size,
                              hipStream_t stream) {
    const float* off  = (const float*)d_in[0];
    const float* nrm  = (const float*)d_in[1];
    const float* curv = (const float*)d_in[2];
    const int*   mask = (const int*)d_in[3];
    float* out = (float*)d_out;

    char* ws = (char*)d_ws;
    float* dm = (float*)(ws + 64);                 // 409600 B
    double* psum = (double*)(ws + 64 + 409600);    // 1600 * 8 B
    unsigned* pcnt = (unsigned*)(ws + 64 + 409600 + NBLK * 8);  // 1600 * 4 B

    k_pre<<<dim3(NPT / 16, NPT / 16), 256, 0, stream>>>(off, nrm, curv, dm);
    k_trip<<<NBLK, 256, 0, stream>>>(mask, dm, psum, pcnt);
    k_fin<<<1, 256, 0, stream>>>(psum, pcnt, out);
}